// Round 4
// baseline (15531.194 us; speedup 1.0000x reference)
//
#include <hip/hip_runtime.h>
#include <hip/hip_bf16.h>

#define N_NODES 10000
#define N_EDGES 160000
#define N_GRAPHS 64
#define NK 5
#define EPS 1e-5f
#define EPB 128          // edges per block
#define JP 768           // padded edge-MLP width (642 -> 768), pads are true zeros
#define CHC 64           // cols per chunk
#define NCH 12           // JP / CHC
#define PSTRIDE 1536     // Pab row stride: [Pa 768 | Pb 768]

__device__ __forceinline__ float silu(float x) { return x / (1.0f + __expf(-x)); }
__device__ __forceinline__ float4 f4fma(float s, float4 w, float4 a) {
    a.x = fmaf(s, w.x, a.x); a.y = fmaf(s, w.y, a.y);
    a.z = fmaf(s, w.z, a.z); a.w = fmaf(s, w.w, a.w);
    return a;
}
__device__ __forceinline__ float wave_sum64(float v) {
    #pragma unroll
    for (int off = 32; off > 0; off >>= 1) v += __shfl_xor(v, off, 64);
    return v;
}

// ---------------- embedding ----------------
__global__ __launch_bounds__(128) void k_embed(const int* __restrict__ atomids,
                                               const float* __restrict__ emb_w,
                                               float* __restrict__ feats_all) {
    int n = blockIdx.x, tid = threadIdx.x;
    feats_all[(size_t)n * 768 + tid] = emb_w[(size_t)atomids[n] * 128 + tid];
}

// ---------------- fourier table, transposed: feT[k][e] ----------------
__global__ __launch_bounds__(64) void k_fe(const float* __restrict__ coords,
                                           const int* __restrict__ eidx,
                                           float* __restrict__ feT) {
    int e = blockIdx.x * 64 + threadIdx.x;
    if (e >= N_EDGES) return;
    int s = eidx[e], d = eidx[N_EDGES + e];
    float dx = coords[s * 3 + 0] - coords[d * 3 + 0];
    float dy = coords[s * 3 + 1] - coords[d * 3 + 1];
    float dz = coords[s * 3 + 2] - coords[d * 3 + 2];
    float d2 = dx * dx + dy * dy + dz * dz;
    float sc = 1.0f;
    #pragma unroll
    for (int i = 0; i < 32; ++i) {
        float x = d2 * sc;
        feT[(size_t)i * N_EDGES + e] = sinf(x);
        feT[(size_t)(32 + i) * N_EDGES + e] = cosf(x);
        sc *= 0.5f;
    }
    feT[(size_t)64 * N_EDGES + e] = d2;
}

// ---------------- W1ab prestage: [128][1536] = [W1a | 0 | W1b | 0] ----------------
__global__ __launch_bounds__(256) void k_w1ab(const float* __restrict__ W1,  // [321][642]
                                              float* __restrict__ W1ab) {
    int idx = blockIdx.x * 256 + threadIdx.x;
    if (idx >= 128 * 1536) return;
    int r = idx >> 10 ? idx / 1536 : idx / 1536;  // plain divide
    r = idx / 1536;
    int j = idx - r * 1536;
    float v = 0.f;
    if (j < 642) v = W1[(size_t)r * 642 + j];
    else if (j >= 768 && j < 1410) v = W1[(size_t)(128 + r) * 642 + (j - 768)];
    W1ab[idx] = v;
}

// ---------------- fp32 GEMM: C = act(actA(A)[M][K] @ B[K][N] + bias) ----------------
// 128x128 tile, 256 threads, 8x8 micro (cols split 4+4, 64 apart).
// Requires: K%32==0, lda%4==0, ldb%4==0, N%4==0, 16B-aligned pointers.
__global__ __launch_bounds__(256) void k_gemm(const float* __restrict__ A, int lda,
                                              const float* __restrict__ B, int ldb,
                                              const float* __restrict__ bias,
                                              float* __restrict__ C, int ldc,
                                              int M, int N, int K, int siluA, int siluOut) {
    __shared__ float As[32 * 132];
    __shared__ float Bs[32 * 132];
    const int tid = threadIdx.x;
    const int m0 = blockIdx.x * 128, n0 = blockIdx.y * 128;
    const int tm = tid >> 4, tn = tid & 15;

    float4 acc[8][2];
    #pragma unroll
    for (int r = 0; r < 8; ++r) { acc[r][0] = make_float4(0,0,0,0); acc[r][1] = make_float4(0,0,0,0); }

    for (int kc = 0; kc < K; kc += 32) {
        #pragma unroll
        for (int i = 0; i < 4; ++i) {
            int idx = tid + i * 256;
            int m = idx >> 3, kq = idx & 7;
            int gm = m0 + m;
            int cm = (gm < M) ? gm : (M - 1);
            float4 a = *(const float4*)(A + (size_t)cm * lda + kc + 4 * kq);
            if (gm >= M) a = make_float4(0,0,0,0);
            if (siluA) { a.x = silu(a.x); a.y = silu(a.y); a.z = silu(a.z); a.w = silu(a.w); }
            As[(4 * kq + 0) * 132 + m] = a.x;
            As[(4 * kq + 1) * 132 + m] = a.y;
            As[(4 * kq + 2) * 132 + m] = a.z;
            As[(4 * kq + 3) * 132 + m] = a.w;
        }
        #pragma unroll
        for (int i = 0; i < 4; ++i) {
            int idx = tid + i * 256;
            int r = idx >> 5, cq = idx & 31;
            int gn = n0 + 4 * cq;
            float4 b = make_float4(0,0,0,0);
            if (gn < N) b = *(const float4*)(B + (size_t)(kc + r) * ldb + gn);
            *(float4*)&Bs[r * 132 + 4 * cq] = b;
        }
        __syncthreads();
        #pragma unroll 4
        for (int kk = 0; kk < 32; ++kk) {
            float4 a0 = *(const float4*)&As[kk * 132 + 8 * tm];
            float4 a1 = *(const float4*)&As[kk * 132 + 8 * tm + 4];
            float4 b0 = *(const float4*)&Bs[kk * 132 + 4 * tn];
            float4 b1 = *(const float4*)&Bs[kk * 132 + 64 + 4 * tn];
            acc[0][0] = f4fma(a0.x, b0, acc[0][0]); acc[0][1] = f4fma(a0.x, b1, acc[0][1]);
            acc[1][0] = f4fma(a0.y, b0, acc[1][0]); acc[1][1] = f4fma(a0.y, b1, acc[1][1]);
            acc[2][0] = f4fma(a0.z, b0, acc[2][0]); acc[2][1] = f4fma(a0.z, b1, acc[2][1]);
            acc[3][0] = f4fma(a0.w, b0, acc[3][0]); acc[3][1] = f4fma(a0.w, b1, acc[3][1]);
            acc[4][0] = f4fma(a1.x, b0, acc[4][0]); acc[4][1] = f4fma(a1.x, b1, acc[4][1]);
            acc[5][0] = f4fma(a1.y, b0, acc[5][0]); acc[5][1] = f4fma(a1.y, b1, acc[5][1]);
            acc[6][0] = f4fma(a1.z, b0, acc[6][0]); acc[6][1] = f4fma(a1.z, b1, acc[6][1]);
            acc[7][0] = f4fma(a1.w, b0, acc[7][0]); acc[7][1] = f4fma(a1.w, b1, acc[7][1]);
        }
        __syncthreads();
    }

    const int gnl = n0 + 4 * tn, gnh = n0 + 64 + 4 * tn;
    #pragma unroll
    for (int r = 0; r < 8; ++r) {
        int gm = m0 + 8 * tm + r;
        if (gm >= M) continue;
        float4 v0 = acc[r][0], v1 = acc[r][1];
        if (gnl < N) {
            if (bias) { v0.x += bias[gnl+0]; v0.y += bias[gnl+1]; v0.z += bias[gnl+2]; v0.w += bias[gnl+3]; }
            if (siluOut) { v0.x = silu(v0.x); v0.y = silu(v0.y); v0.z = silu(v0.z); v0.w = silu(v0.w); }
            *(float4*)&C[(size_t)gm * ldc + gnl] = v0;
        }
        if (gnh < N) {
            if (bias) { v1.x += bias[gnh+0]; v1.y += bias[gnh+1]; v1.z += bias[gnh+2]; v1.w += bias[gnh+3]; }
            if (siluOut) { v1.x = silu(v1.x); v1.y = silu(v1.y); v1.z = silu(v1.z); v1.w = silu(v1.w); }
            *(float4*)&C[(size_t)gm * ldc + gnh] = v1;
        }
    }
}

// ---------------- fused edge kernel, register-z + LDS-atomic m2 ----------------
// 128 edges/block, 12 chunks of 64 cols. Thread = 4 edges x 8 cols.
// Phase1: q = fe@W1chunk, z = silu(q + Pa[dst] + Pb[src] + b1) in REGISTERS.
// Phase2: partial m2 over own 8 j's -> ds_add_f32 into m2s. Epilogue: +b2, silu, LN, scatter.
__global__ __launch_bounds__(256, 2) void k_edge(const float* __restrict__ feT,   // [65][N_EDGES]
                                                 const float* __restrict__ Pab,   // [N_NODES][1536]
                                                 const int* __restrict__ eidx,
                                                 const float* __restrict__ W1c,   // [65][642]
                                                 const float* __restrict__ b1,    // [642]
                                                 const float* __restrict__ W2,    // [642][32]
                                                 const float* __restrict__ b2,
                                                 const float* __restrict__ eng,
                                                 const float* __restrict__ enb,
                                                 float* __restrict__ S,
                                                 float* __restrict__ cnt) {
    __shared__ float feTs[65 * 132];   // [k][e], 34320 B
    __shared__ float W1s[33 * 68];     // [kk][j] half-staged, 8976 B
    __shared__ float W2s[64 * 36];     // [j][c], 9216 B
    __shared__ float m2s[128 * 33];    // accumulators, 16896 B
    __shared__ float b1s[JP];          // 3072 B
    __shared__ int dsi[EPB], ssi[EPB]; // 1024 B
    __shared__ float cpar[96];         // b2 | eng | enb

    const int tid = threadIdx.x;
    const int eb = blockIdx.x * EPB;
    const int et = tid & 31, cg = tid >> 5;   // edges 4*et.., cols 8*cg.. (in chunk)
    const int e0 = 4 * et;

    if (tid < EPB) {
        ssi[tid] = eidx[eb + tid];
        dsi[tid] = eidx[N_EDGES + eb + tid];
    }
    for (int j = tid; j < JP; j += 256) b1s[j] = (j < 642) ? b1[j] : 0.f;
    if (tid < 32) cpar[tid] = b2[tid];
    else if (tid < 64) cpar[tid] = eng[tid - 32];
    else if (tid < 96) cpar[tid] = enb[tid - 64];
    for (int idx = tid; idx < 128 * 33; idx += 256) m2s[idx] = 0.f;
    for (int idx = tid; idx < 65 * 32; idx += 256) {
        int k = idx >> 5, q = idx & 31;
        *(float4*)&feTs[k * 132 + 4 * q] = *(const float4*)(feT + (size_t)k * N_EDGES + eb + 4 * q);
    }

    for (int ch = 0; ch < NCH; ++ch) {
        const int jc = ch * CHC;
        __syncthreads();   // init / previous chunk's phase2 complete

        // stage W2s [64][32]
        #pragma unroll
        for (int i = 0; i < 2; ++i) {
            int idx = tid + i * 256;
            int j = idx >> 3, q = idx & 7;
            int gj = jc + j;
            float4 w = make_float4(0,0,0,0);
            if (gj < 642) w = *(const float4*)(W2 + (size_t)gj * 32 + 4 * q);
            *(float4*)&W2s[j * 36 + 4 * q] = w;
        }
        // stage W1s rows 0..32
        for (int idx = tid; idx < 33 * 64; idx += 256) {
            int kk = idx >> 6, j = idx & 63;
            int gj = jc + j;
            W1s[kk * 68 + j] = (gj < 642) ? W1c[(size_t)kk * 642 + gj] : 0.f;
        }
        // prefetch gathers (complete during k-loop)
        float pav[4][8], pbv[4][8];
        #pragma unroll
        for (int i = 0; i < 4; ++i) {
            const float* pr = Pab + (size_t)dsi[e0 + i] * PSTRIDE + jc + 8 * cg;
            *(float4*)&pav[i][0] = *(const float4*)pr;
            *(float4*)&pav[i][4] = *(const float4*)(pr + 4);
            const float* qr = Pab + (size_t)ssi[e0 + i] * PSTRIDE + JP + jc + 8 * cg;
            *(float4*)&pbv[i][0] = *(const float4*)qr;
            *(float4*)&pbv[i][4] = *(const float4*)(qr + 4);
        }

        float qa[4][8];
        #pragma unroll
        for (int i = 0; i < 4; ++i)
            #pragma unroll
            for (int c = 0; c < 8; ++c) qa[i][c] = 0.f;

        __syncthreads();
        // k half 0: rows 0..32
        #pragma unroll 3
        for (int kk = 0; kk < 33; ++kk) {
            float4 f  = *(const float4*)&feTs[kk * 132 + 4 * et];
            float4 w0 = *(const float4*)&W1s[kk * 68 + 8 * cg];
            float4 w1 = *(const float4*)&W1s[kk * 68 + 8 * cg + 4];
            float fv[4] = {f.x, f.y, f.z, f.w};
            float wv[8] = {w0.x, w0.y, w0.z, w0.w, w1.x, w1.y, w1.z, w1.w};
            #pragma unroll
            for (int i = 0; i < 4; ++i)
                #pragma unroll
                for (int c = 0; c < 8; ++c) qa[i][c] = fmaf(fv[i], wv[c], qa[i][c]);
        }
        __syncthreads();
        // stage W1s rows 33..64
        for (int idx = tid; idx < 32 * 64; idx += 256) {
            int kk = idx >> 6, j = idx & 63;
            int gj = jc + j;
            W1s[kk * 68 + j] = (gj < 642) ? W1c[(size_t)(33 + kk) * 642 + gj] : 0.f;
        }
        __syncthreads();
        #pragma unroll 4
        for (int kk = 0; kk < 32; ++kk) {
            float4 f  = *(const float4*)&feTs[(33 + kk) * 132 + 4 * et];
            float4 w0 = *(const float4*)&W1s[kk * 68 + 8 * cg];
            float4 w1 = *(const float4*)&W1s[kk * 68 + 8 * cg + 4];
            float fv[4] = {f.x, f.y, f.z, f.w};
            float wv[8] = {w0.x, w0.y, w0.z, w0.w, w1.x, w1.y, w1.z, w1.w};
            #pragma unroll
            for (int i = 0; i < 4; ++i)
                #pragma unroll
                for (int c = 0; c < 8; ++c) qa[i][c] = fmaf(fv[i], wv[c], qa[i][c]);
        }

        // z = silu(q + pa + pb + b1) in registers
        float bv[8];
        *(float4*)&bv[0] = *(const float4*)&b1s[jc + 8 * cg];
        *(float4*)&bv[4] = *(const float4*)&b1s[jc + 8 * cg + 4];
        #pragma unroll
        for (int i = 0; i < 4; ++i)
            #pragma unroll
            for (int c = 0; c < 8; ++c)
                qa[i][c] = silu(qa[i][c] + pav[i][c] + pbv[i][c] + bv[c]);

        // phase2: m2 partials over own 8 j's, cg-staggered cb to avoid same-addr atomics
        #pragma unroll
        for (int cb = 0; cb < 8; ++cb) {
            const int cbb = (cb + cg) & 7;
            float p[4][4];
            #pragma unroll
            for (int i = 0; i < 4; ++i)
                #pragma unroll
                for (int cc = 0; cc < 4; ++cc) p[i][cc] = 0.f;
            #pragma unroll
            for (int jj = 0; jj < 8; ++jj) {
                float4 w = *(const float4*)&W2s[(8 * cg + jj) * 36 + 4 * cbb];
                float wv[4] = {w.x, w.y, w.z, w.w};
                #pragma unroll
                for (int i = 0; i < 4; ++i)
                    #pragma unroll
                    for (int cc = 0; cc < 4; ++cc)
                        p[i][cc] = fmaf(qa[i][jj], wv[cc], p[i][cc]);
            }
            #pragma unroll
            for (int i = 0; i < 4; ++i)
                #pragma unroll
                for (int cc = 0; cc < 4; ++cc)
                    atomicAdd(&m2s[(e0 + i) * 33 + 4 * cbb + cc], p[i][cc]);
        }
    }
    __syncthreads();

    // epilogue: one thread per edge
    if (tid < EPB) {
        float v[32];
        float s = 0.f, ss = 0.f;
        #pragma unroll
        for (int c = 0; c < 32; ++c) {
            float x = silu(m2s[tid * 33 + c] + cpar[c]);
            v[c] = x; s += x; ss += x * x;
        }
        float mean = s * 0.03125f;
        float var = ss * 0.03125f - mean * mean;
        float rstd = 1.0f / sqrtf(var + EPS);
        int d = dsi[tid];
        float* Sp = S + (size_t)d * 32;
        #pragma unroll
        for (int c = 0; c < 32; ++c) {
            float y = (v[c] - mean) * rstd * cpar[32 + c] + cpar[64 + c];
            atomicAdd(&Sp[c], y);
        }
        atomicAdd(&cnt[d], 1.0f);
    }
}

// ---------------- node prep: H0 = [LN(feats) | LN(S/cnt)] ----------------
__global__ __launch_bounds__(128) void k_prep(const float* __restrict__ featsk,
                                              const float* __restrict__ S,
                                              const float* __restrict__ cnt,
                                              const float* __restrict__ nn1g,
                                              const float* __restrict__ nn1b,
                                              const float* __restrict__ eng,
                                              const float* __restrict__ enb,
                                              float* __restrict__ H0) {
    int n = blockIdx.x, tid = threadIdx.x;
    __shared__ float red[4];
    float x = featsk[(size_t)n * 768 + tid];
    float s = wave_sum64(x), ss = wave_sum64(x * x);
    if ((tid & 63) == 0) { red[(tid >> 6) * 2] = s; red[(tid >> 6) * 2 + 1] = ss; }
    __syncthreads();
    float S1 = red[0] + red[2], S2 = red[1] + red[3];
    float mean = S1 * (1.0f / 128.0f);
    float var = S2 * (1.0f / 128.0f) - mean * mean;
    float rstd = 1.0f / sqrtf(var + EPS);
    H0[(size_t)n * 160 + tid] = (x - mean) * rstd * nn1g[tid] + nn1b[tid];
    if (tid < 32) {
        float inv = 1.0f / fmaxf(cnt[n], 1.0f);
        float v = S[(size_t)n * 32 + tid] * inv;
        float s2 = v, q2 = v * v;
        #pragma unroll
        for (int off = 16; off > 0; off >>= 1) {
            s2 += __shfl_xor(s2, off, 64);
            q2 += __shfl_xor(q2, off, 64);
        }
        float m2 = s2 * (1.0f / 32.0f);
        float va = q2 * (1.0f / 32.0f) - m2 * m2;
        float rs = 1.0f / sqrtf(va + EPS);
        H0[(size_t)n * 160 + 128 + tid] = (v - m2) * rs * eng[tid] + enb[tid];
    }
}

// ---------------- LN + residual ----------------
__global__ __launch_bounds__(128) void k_ln_res(const float* __restrict__ H2,
                                                float* __restrict__ feats_all, int k,
                                                const float* __restrict__ g,
                                                const float* __restrict__ b) {
    int n = blockIdx.x, tid = threadIdx.x;
    __shared__ float red[4];
    float x = H2[(size_t)n * 128 + tid];
    float s = wave_sum64(x), ss = wave_sum64(x * x);
    if ((tid & 63) == 0) { red[(tid >> 6) * 2] = s; red[(tid >> 6) * 2 + 1] = ss; }
    __syncthreads();
    float S1 = red[0] + red[2], S2 = red[1] + red[3];
    float mean = S1 * (1.0f / 128.0f);
    float var = S2 * (1.0f / 128.0f) - mean * mean;
    float rstd = 1.0f / sqrtf(var + EPS);
    float v = (x - mean) * rstd * g[tid] + b[tid];
    float f = feats_all[(size_t)n * 768 + k * 128 + tid];
    feats_all[(size_t)n * 768 + (k + 1) * 128 + tid] = f + v;
}

// ---------------- graph pooling (batch sorted -> run-length accum) ----------------
__global__ __launch_bounds__(256) void k_pool(const float* __restrict__ F,
                                              const int* __restrict__ batch,
                                              float* __restrict__ G,
                                              float* __restrict__ cntg) {
    __shared__ int bL[32];
    int b0 = blockIdx.x * 32;
    int tid = threadIdx.x;
    int nmax = min(32, N_NODES - b0);
    if (nmax <= 0) return;
    if (tid < nmax) bL[tid] = batch[b0 + tid];
    __syncthreads();
    float accv = 0.f;
    int cur = -1;
    for (int i = 0; i < nmax; ++i) {
        int g = bL[i];
        if (g != cur) {
            if (cur >= 0) atomicAdd(&G[(size_t)cur * 256 + tid], accv);
            cur = g; accv = 0.f;
        }
        accv += F[(size_t)(b0 + i) * 256 + tid];
    }
    if (cur >= 0) atomicAdd(&G[(size_t)cur * 256 + tid], accv);
    if (tid == 0)
        for (int i = 0; i < nmax; ++i) atomicAdd(&cntg[bL[i]], 1.0f);
}

// ---------------- per-graph MLP head ----------------
__global__ __launch_bounds__(256) void k_graph(const float* __restrict__ G,
                                               const float* __restrict__ cntg,
                                               const float* __restrict__ g1W,
                                               const float* __restrict__ g1b,
                                               const float* __restrict__ g2W,
                                               const float* __restrict__ g2b,
                                               const float* __restrict__ g3W,
                                               const float* __restrict__ g3b,
                                               float* __restrict__ out) {
    __shared__ float X[256], Y[256], red[4];
    int g = blockIdx.x, tid = threadIdx.x;
    float inv = 1.0f / fmaxf(cntg[g], 1.0f);
    X[tid] = G[(size_t)g * 256 + tid] * inv;
    __syncthreads();
    float a = g1b[tid];
    for (int j = 0; j < 256; ++j) a = fmaf(X[j], g1W[(size_t)j * 256 + tid], a);
    Y[tid] = silu(a);
    __syncthreads();
    a = g2b[tid];
    for (int j = 0; j < 256; ++j) a = fmaf(Y[j], g2W[(size_t)j * 256 + tid], a);
    float z = silu(a);
    float p = z * g3W[tid];
    p = wave_sum64(p);
    if ((tid & 63) == 0) red[tid >> 6] = p;
    __syncthreads();
    if (tid == 0) out[g] = red[0] + red[1] + red[2] + red[3] + g3b[0];
}

extern "C" void kernel_launch(void* const* d_in, const int* in_sizes, int n_in,
                              void* d_out, int out_size, void* d_ws, size_t ws_size,
                              hipStream_t stream) {
    const int*   atomids = (const int*)d_in[0];
    const float* coords  = (const float*)d_in[1];
    const int*   eidx    = (const int*)d_in[2];
    const int*   batch   = (const int*)d_in[3];
    const float* emb_w   = (const float*)d_in[4];
    const float* eW1     = (const float*)d_in[5];
    const float* eb1     = (const float*)d_in[6];
    const float* eW2     = (const float*)d_in[7];
    const float* eb2     = (const float*)d_in[8];
    const float* en_g    = (const float*)d_in[9];
    const float* en_b    = (const float*)d_in[10];
    const float* nn1_g   = (const float*)d_in[11];
    const float* nn1_b   = (const float*)d_in[12];
    const float* nW1     = (const float*)d_in[13];
    const float* nb1     = (const float*)d_in[14];
    const float* nW2     = (const float*)d_in[15];
    const float* nb2     = (const float*)d_in[16];
    const float* nn2_g   = (const float*)d_in[17];
    const float* nn2_b   = (const float*)d_in[18];
    const float* f1W     = (const float*)d_in[19];
    const float* f1b     = (const float*)d_in[20];
    const float* f2W     = (const float*)d_in[21];
    const float* f2b     = (const float*)d_in[22];
    const float* f3W     = (const float*)d_in[23];
    const float* f3b     = (const float*)d_in[24];
    const float* g1W     = (const float*)d_in[25];
    const float* g1b     = (const float*)d_in[26];
    const float* g2W     = (const float*)d_in[27];
    const float* g2b     = (const float*)d_in[28];
    const float* g3W     = (const float*)d_in[29];
    const float* g3b     = (const float*)d_in[30];
    float* out = (float*)d_out;

    float* ws = (float*)d_ws;
    // layout (float indices, all 16B-aligned); total ~135.9 MB
    float* feats_all = ws;                        // [10000][768]
    float* feT   = ws + 7680000;                  // [65][160000]
    float* Pab   = ws + 18080000;                 // [10000][1536]
    float* S     = ws + 33440000;                 // [10000][32]
    float* cnt   = ws + 33760000;                 // [10000]
    float* W1ab  = ws + 33770000;                 // [128][1536]
    float* G     = ws + 33966608;                 // [64][256]
    float* cntg  = ws + 33982992;                 // [64]
    // node-phase temporaries overlay Pab (dead between phases)
    float* H0 = Pab;                              // [10000][160]
    float* H1 = Pab + 1600000;                    // [10000][256]
    float* H2 = Pab + 4160000;                    // [10000][128]
    float* F1 = Pab;                              // [10000][256]
    float* F2 = Pab + 2560000;                    // [10000][256]
    float* F3 = Pab + 5120000;                    // [10000][256]

    k_embed<<<N_NODES, 128, 0, stream>>>(atomids, emb_w, feats_all);
    k_fe<<<N_EDGES / 64, 64, 0, stream>>>(coords, eidx, feT);

    for (int k = 0; k < NK; ++k) {
        const float* eW1k = eW1 + (size_t)k * 321 * 642;
        const float* eb1k = eb1 + (size_t)k * 642;
        const float* eW2k = eW2 + (size_t)k * 642 * 32;
        const float* eb2k = eb2 + (size_t)k * 32;
        const float* engk = en_g + (size_t)k * 32;
        const float* enbk = en_b + (size_t)k * 32;
        const float* nn1gk = nn1_g + (size_t)k * 128;
        const float* nn1bk = nn1_b + (size_t)k * 128;
        const float* nW1k = nW1 + (size_t)k * 160 * 256;
        const float* nb1k = nb1 + (size_t)k * 256;
        const float* nW2k = nW2 + (size_t)k * 256 * 128;
        const float* nb2k = nb2 + (size_t)k * 128;
        const float* nn2gk = nn2_g + (size_t)k * 128;
        const float* nn2bk = nn2_b + (size_t)k * 128;

        k_w1ab<<<768, 256, 0, stream>>>(eW1k, W1ab);
        k_gemm<<<dim3(79, 12), 256, 0, stream>>>(feats_all + k * 128, 768, W1ab, 1536,
                                                 nullptr, Pab, 1536, N_NODES, 1536, 128, 0, 0);
        hipMemsetAsync(S, 0, (size_t)330000 * sizeof(float), stream);
        k_edge<<<N_EDGES / EPB, 256, 0, stream>>>(feT, Pab, eidx, eW1k + 256 * 642, eb1k,
                                                  eW2k, eb2k, engk, enbk, S, cnt);
        k_prep<<<N_NODES, 128, 0, stream>>>(feats_all + k * 128, S, cnt,
                                            nn1gk, nn1bk, engk, enbk, H0);
        k_gemm<<<dim3(79, 2), 256, 0, stream>>>(H0, 160, nW1k, 256, nb1k, H1, 256,
                                                N_NODES, 256, 160, 0, 1);
        k_gemm<<<dim3(79, 1), 256, 0, stream>>>(H1, 256, nW2k, 128, nb2k, H2, 128,
                                                N_NODES, 128, 256, 0, 0);
        k_ln_res<<<N_NODES, 128, 0, stream>>>(H2, feats_all, k, nn2gk, nn2bk);
    }

    // final node MLP (F1/F2/F3 overlay Pab)
    k_gemm<<<dim3(79, 2), 256, 0, stream>>>(feats_all, 768, f1W, 256, f1b, F1, 256,
                                            N_NODES, 256, 768, 1, 1);
    k_gemm<<<dim3(79, 2), 256, 0, stream>>>(F1, 256, f2W, 256, f2b, F2, 256,
                                            N_NODES, 256, 256, 0, 1);
    k_gemm<<<dim3(79, 2), 256, 0, stream>>>(F2, 256, f3W, 256, f3b, F3, 256,
                                            N_NODES, 256, 256, 0, 1);

    hipMemsetAsync(G, 0, (size_t)(16384 + 64) * sizeof(float), stream);
    k_pool<<<313, 256, 0, stream>>>(F3, batch, G, cntg);
    k_graph<<<N_GRAPHS, 256, 0, stream>>>(G, cntg, g1W, g1b, g2W, g2b, g3W, g3b, out);
}

// Round 5
// 4256.521 us; speedup vs baseline: 3.6488x; 3.6488x over previous
//
#include <hip/hip_runtime.h>
#include <hip/hip_bf16.h>

#define N_NODES 10000
#define N_EDGES 160000
#define N_GRAPHS 64
#define NK 5
#define EPS 1e-5f
#define EPB 128          // edges per block
#define JP 768           // padded edge-MLP width (642 -> 768), pads are true zeros
#define CHC 128          // cols per chunk
#define NCH 6            // JP / CHC
#define PSTRIDE 1536     // Pab row stride: [Pa 768 | Pb 768]

__device__ __forceinline__ float silu(float x) { return x / (1.0f + __expf(-x)); }
__device__ __forceinline__ float4 f4fma(float s, float4 w, float4 a) {
    a.x = fmaf(s, w.x, a.x); a.y = fmaf(s, w.y, a.y);
    a.z = fmaf(s, w.z, a.z); a.w = fmaf(s, w.w, a.w);
    return a;
}
__device__ __forceinline__ float wave_sum64(float v) {
    #pragma unroll
    for (int off = 32; off > 0; off >>= 1) v += __shfl_xor(v, off, 64);
    return v;
}

// ---------------- embedding ----------------
__global__ __launch_bounds__(128) void k_embed(const int* __restrict__ atomids,
                                               const float* __restrict__ emb_w,
                                               float* __restrict__ feats_all) {
    int n = blockIdx.x, tid = threadIdx.x;
    feats_all[(size_t)n * 768 + tid] = emb_w[(size_t)atomids[n] * 128 + tid];
}

// ---------------- fourier table, transposed: feT[k][e] ----------------
__global__ __launch_bounds__(64) void k_fe(const float* __restrict__ coords,
                                           const int* __restrict__ eidx,
                                           float* __restrict__ feT) {
    int e = blockIdx.x * 64 + threadIdx.x;
    if (e >= N_EDGES) return;
    int s = eidx[e], d = eidx[N_EDGES + e];
    float dx = coords[s * 3 + 0] - coords[d * 3 + 0];
    float dy = coords[s * 3 + 1] - coords[d * 3 + 1];
    float dz = coords[s * 3 + 2] - coords[d * 3 + 2];
    float d2 = dx * dx + dy * dy + dz * dz;
    float sc = 1.0f;
    #pragma unroll
    for (int i = 0; i < 32; ++i) {
        float x = d2 * sc;
        feT[(size_t)i * N_EDGES + e] = sinf(x);
        feT[(size_t)(32 + i) * N_EDGES + e] = cosf(x);
        sc *= 0.5f;
    }
    feT[(size_t)64 * N_EDGES + e] = d2;
}

// ---------------- W1ab prestage: [128][1536] = [W1a | 0 | W1b | 0] ----------------
__global__ __launch_bounds__(256) void k_w1ab(const float* __restrict__ W1,  // [321][642]
                                              float* __restrict__ W1ab) {
    int idx = blockIdx.x * 256 + threadIdx.x;
    if (idx >= 128 * 1536) return;
    int r = idx / 1536;
    int j = idx - r * 1536;
    float v = 0.f;
    if (j < 642) v = W1[(size_t)r * 642 + j];
    else if (j >= 768 && j < 1410) v = W1[(size_t)(128 + r) * 642 + (j - 768)];
    W1ab[idx] = v;
}

// ---------------- padded edge-weight prestage ----------------
// W1cp[65][768] from W1 rows 256..320 ; b1p[768] ; W2p[768][32]
__global__ __launch_bounds__(256) void k_wpre(const float* __restrict__ W1,   // [321][642]
                                              const float* __restrict__ b1,   // [642]
                                              const float* __restrict__ W2,   // [642][32]
                                              float* __restrict__ W1cp,
                                              float* __restrict__ b1p,
                                              float* __restrict__ W2p) {
    int idx = blockIdx.x * 256 + threadIdx.x;
    if (idx < 65 * 768) {
        int r = idx / 768, j = idx - r * 768;
        W1cp[idx] = (j < 642) ? W1[(size_t)(256 + r) * 642 + j] : 0.f;
    } else if (idx < 65 * 768 + 768) {
        int j = idx - 65 * 768;
        b1p[j] = (j < 642) ? b1[j] : 0.f;
    } else if (idx < 65 * 768 + 768 + 768 * 32) {
        int t = idx - (65 * 768 + 768);
        int j = t >> 5, c = t & 31;
        W2p[t] = (j < 642) ? W2[(size_t)j * 32 + c] : 0.f;
    }
}

// ---------------- fp32 GEMM: C = act(actA(A)[M][K] @ B[K][N] + bias) ----------------
// 128x128 tile, 256 threads, 8x8 micro (cols split 4+4, 64 apart).
// Requires: K%32==0, lda%4==0, ldb%4==0, N%4==0, 16B-aligned pointers.
__global__ __launch_bounds__(256) void k_gemm(const float* __restrict__ A, int lda,
                                              const float* __restrict__ B, int ldb,
                                              const float* __restrict__ bias,
                                              float* __restrict__ C, int ldc,
                                              int M, int N, int K, int siluA, int siluOut) {
    __shared__ float As[32 * 132];
    __shared__ float Bs[32 * 132];
    const int tid = threadIdx.x;
    const int m0 = blockIdx.x * 128, n0 = blockIdx.y * 128;
    const int tm = tid >> 4, tn = tid & 15;

    float4 acc[8][2];
    #pragma unroll
    for (int r = 0; r < 8; ++r) { acc[r][0] = make_float4(0,0,0,0); acc[r][1] = make_float4(0,0,0,0); }

    for (int kc = 0; kc < K; kc += 32) {
        #pragma unroll
        for (int i = 0; i < 4; ++i) {
            int idx = tid + i * 256;
            int m = idx >> 3, kq = idx & 7;
            int gm = m0 + m;
            int cm = (gm < M) ? gm : (M - 1);
            float4 a = *(const float4*)(A + (size_t)cm * lda + kc + 4 * kq);
            if (gm >= M) a = make_float4(0,0,0,0);
            if (siluA) { a.x = silu(a.x); a.y = silu(a.y); a.z = silu(a.z); a.w = silu(a.w); }
            As[(4 * kq + 0) * 132 + m] = a.x;
            As[(4 * kq + 1) * 132 + m] = a.y;
            As[(4 * kq + 2) * 132 + m] = a.z;
            As[(4 * kq + 3) * 132 + m] = a.w;
        }
        #pragma unroll
        for (int i = 0; i < 4; ++i) {
            int idx = tid + i * 256;
            int r = idx >> 5, cq = idx & 31;
            int gn = n0 + 4 * cq;
            float4 b = make_float4(0,0,0,0);
            if (gn < N) b = *(const float4*)(B + (size_t)(kc + r) * ldb + gn);
            *(float4*)&Bs[r * 132 + 4 * cq] = b;
        }
        __syncthreads();
        #pragma unroll 4
        for (int kk = 0; kk < 32; ++kk) {
            float4 a0 = *(const float4*)&As[kk * 132 + 8 * tm];
            float4 a1 = *(const float4*)&As[kk * 132 + 8 * tm + 4];
            float4 b0 = *(const float4*)&Bs[kk * 132 + 4 * tn];
            float4 b1 = *(const float4*)&Bs[kk * 132 + 64 + 4 * tn];
            acc[0][0] = f4fma(a0.x, b0, acc[0][0]); acc[0][1] = f4fma(a0.x, b1, acc[0][1]);
            acc[1][0] = f4fma(a0.y, b0, acc[1][0]); acc[1][1] = f4fma(a0.y, b1, acc[1][1]);
            acc[2][0] = f4fma(a0.z, b0, acc[2][0]); acc[2][1] = f4fma(a0.z, b1, acc[2][1]);
            acc[3][0] = f4fma(a0.w, b0, acc[3][0]); acc[3][1] = f4fma(a0.w, b1, acc[3][1]);
            acc[4][0] = f4fma(a1.x, b0, acc[4][0]); acc[4][1] = f4fma(a1.x, b1, acc[4][1]);
            acc[5][0] = f4fma(a1.y, b0, acc[5][0]); acc[5][1] = f4fma(a1.y, b1, acc[5][1]);
            acc[6][0] = f4fma(a1.z, b0, acc[6][0]); acc[6][1] = f4fma(a1.z, b1, acc[6][1]);
            acc[7][0] = f4fma(a1.w, b0, acc[7][0]); acc[7][1] = f4fma(a1.w, b1, acc[7][1]);
        }
        __syncthreads();
    }

    const int gnl = n0 + 4 * tn, gnh = n0 + 64 + 4 * tn;
    #pragma unroll
    for (int r = 0; r < 8; ++r) {
        int gm = m0 + 8 * tm + r;
        if (gm >= M) continue;
        float4 v0 = acc[r][0], v1 = acc[r][1];
        if (gnl < N) {
            if (bias) { v0.x += bias[gnl+0]; v0.y += bias[gnl+1]; v0.z += bias[gnl+2]; v0.w += bias[gnl+3]; }
            if (siluOut) { v0.x = silu(v0.x); v0.y = silu(v0.y); v0.z = silu(v0.z); v0.w = silu(v0.w); }
            *(float4*)&C[(size_t)gm * ldc + gnl] = v0;
        }
        if (gnh < N) {
            if (bias) { v1.x += bias[gnh+0]; v1.y += bias[gnh+1]; v1.z += bias[gnh+2]; v1.w += bias[gnh+3]; }
            if (siluOut) { v1.x = silu(v1.x); v1.y = silu(v1.y); v1.z = silu(v1.z); v1.w = silu(v1.w); }
            *(float4*)&C[(size_t)gm * ldc + gnh] = v1;
        }
    }
}

// ---------------- fused edge kernel (8e x 8c phase-1 micro, Zs round-trip phase-2) ----------------
// 128 edges/block, 6 chunks of 128 cols.
// Phase1 (et=tid&15, cg=tid>>4; 8 edges x 8 cols): qa = Pa[dst]+Pb[src]+b1, qa += fe@W1chunk, z=silu(qa).
// Phase2: 4 sub-passes of 32 j: writer wave -> Zs[32][132], all threads (eg=tid>>3: 4e, cq=tid&7: 4c)
//         accm += Zs @ W2s. Epilogue: +b2, silu, LN, atomic segment-add.
__global__ __launch_bounds__(256, 2) void k_edge(const float* __restrict__ feT,   // [65][N_EDGES]
                                                 const float* __restrict__ Pab,   // [N_NODES][1536]
                                                 const int* __restrict__ eidx,
                                                 const float* __restrict__ W1cp,  // [65][768]
                                                 const float* __restrict__ b1p,   // [768]
                                                 const float* __restrict__ W2p,   // [768][32]
                                                 const float* __restrict__ b2,
                                                 const float* __restrict__ eng,
                                                 const float* __restrict__ enb,
                                                 float* __restrict__ S,
                                                 float* __restrict__ cnt) {
    __shared__ float feTs[65 * 132];   // [k][e]   34320 B
    __shared__ float W1s[33 * 132];    // [kk][j]  17424 B (half-staged)
    __shared__ float Zs[32 * 132];     // [j][e]   16896 B ; reused as m2s[128][33]
    __shared__ float W2s[32 * 36];     //           4608 B
    __shared__ int dsi[EPB], ssi[EPB]; //           1024 B
    __shared__ float cpar[96];         // b2|eng|enb 384 B   -> total 74656 B

    const int tid = threadIdx.x;
    const int eb = blockIdx.x * EPB;
    const int et = tid & 15, cg = tid >> 4;    // phase-1: edges 8*et.., cols 8*cg..
    const int eg = tid >> 3, cq = tid & 7;     // phase-2: edges 4*eg.., cols 4*cq..

    if (tid < EPB) {
        ssi[tid] = eidx[eb + tid];
        dsi[tid] = eidx[N_EDGES + eb + tid];
    }
    if (tid < 32) cpar[tid] = b2[tid];
    else if (tid < 64) cpar[tid] = eng[tid - 32];
    else if (tid < 96) cpar[tid] = enb[tid - 64];
    for (int idx = tid; idx < 65 * 32; idx += 256) {
        int k = idx >> 5, q = idx & 31;
        *(float4*)&feTs[k * 132 + 4 * q] = *(const float4*)(feT + (size_t)k * N_EDGES + eb + 4 * q);
    }
    __syncthreads();

    // register-cache this thread's 8 edge indices (phase-1 ownership)
    int dsr[8], ssr[8];
    #pragma unroll
    for (int i = 0; i < 8; ++i) { dsr[i] = dsi[8 * et + i]; ssr[i] = ssi[8 * et + i]; }

    float4 accm[4];
    #pragma unroll
    for (int i = 0; i < 4; ++i) accm[i] = make_float4(0,0,0,0);

    for (int ch = 0; ch < NCH; ++ch) {
        const int jc = ch * CHC;

        // ---- qa init: gathered Pa/Pb + b1 (global, no LDS) ----
        float qa[8][8];
        float4 b1lo = *(const float4*)(b1p + jc + 8 * cg);
        float4 b1hi = *(const float4*)(b1p + jc + 8 * cg + 4);
        #pragma unroll
        for (int i = 0; i < 8; ++i) {
            const float* pr = Pab + (size_t)dsr[i] * PSTRIDE + jc + 8 * cg;
            const float* qr = Pab + (size_t)ssr[i] * PSTRIDE + JP + jc + 8 * cg;
            float4 a0 = *(const float4*)pr;
            float4 a1 = *(const float4*)(pr + 4);
            float4 c0 = *(const float4*)qr;
            float4 c1 = *(const float4*)(qr + 4);
            qa[i][0] = a0.x + c0.x + b1lo.x; qa[i][1] = a0.y + c0.y + b1lo.y;
            qa[i][2] = a0.z + c0.z + b1lo.z; qa[i][3] = a0.w + c0.w + b1lo.w;
            qa[i][4] = a1.x + c1.x + b1hi.x; qa[i][5] = a1.y + c1.y + b1hi.y;
            qa[i][6] = a1.z + c1.z + b1hi.z; qa[i][7] = a1.w + c1.w + b1hi.w;
        }

        // ---- stage W1s rows 0..32 (float4 aligned via W1cp) ----
        __syncthreads();   // W1s/Zs free from previous chunk
        #pragma unroll
        for (int i = 0; i < 5; ++i) {
            int idx = tid + i * 256;
            if (idx < 33 * 32) {
                int r = idx >> 5, q = idx & 31;
                *(float4*)&W1s[r * 132 + 4 * q] = *(const float4*)(W1cp + (size_t)r * 768 + jc + 4 * q);
            }
        }
        __syncthreads();
        for (int kk = 0; kk < 33; ++kk) {
            float4 f0 = *(const float4*)&feTs[kk * 132 + 8 * et];
            float4 f1 = *(const float4*)&feTs[kk * 132 + 8 * et + 4];
            float4 w0 = *(const float4*)&W1s[kk * 132 + 8 * cg];
            float4 w1 = *(const float4*)&W1s[kk * 132 + 8 * cg + 4];
            float fv[8] = {f0.x, f0.y, f0.z, f0.w, f1.x, f1.y, f1.z, f1.w};
            float wv[8] = {w0.x, w0.y, w0.z, w0.w, w1.x, w1.y, w1.z, w1.w};
            #pragma unroll
            for (int i = 0; i < 8; ++i)
                #pragma unroll
                for (int c = 0; c < 8; ++c) qa[i][c] = fmaf(fv[i], wv[c], qa[i][c]);
        }
        __syncthreads();
        // ---- stage W1s rows 33..64 ----
        #pragma unroll
        for (int i = 0; i < 4; ++i) {
            int idx = tid + i * 256;
            if (idx < 32 * 32) {
                int r = idx >> 5, q = idx & 31;
                *(float4*)&W1s[r * 132 + 4 * q] = *(const float4*)(W1cp + (size_t)(33 + r) * 768 + jc + 4 * q);
            }
        }
        __syncthreads();
        for (int kk = 0; kk < 32; ++kk) {
            float4 f0 = *(const float4*)&feTs[(33 + kk) * 132 + 8 * et];
            float4 f1 = *(const float4*)&feTs[(33 + kk) * 132 + 8 * et + 4];
            float4 w0 = *(const float4*)&W1s[kk * 132 + 8 * cg];
            float4 w1 = *(const float4*)&W1s[kk * 132 + 8 * cg + 4];
            float fv[8] = {f0.x, f0.y, f0.z, f0.w, f1.x, f1.y, f1.z, f1.w};
            float wv[8] = {w0.x, w0.y, w0.z, w0.w, w1.x, w1.y, w1.z, w1.w};
            #pragma unroll
            for (int i = 0; i < 8; ++i)
                #pragma unroll
                for (int c = 0; c < 8; ++c) qa[i][c] = fmaf(fv[i], wv[c], qa[i][c]);
        }

        // ---- z = silu(qa) ----
        #pragma unroll
        for (int i = 0; i < 8; ++i)
            #pragma unroll
            for (int c = 0; c < 8; ++c) qa[i][c] = silu(qa[i][c]);

        // ---- phase 2: 4 sub-passes of 32 j ----
        #pragma unroll
        for (int p = 0; p < 4; ++p) {
            __syncthreads();   // previous pass reads / phase-1 W1s reads done
            if ((cg >> 2) == p) {
                int jl = 8 * (cg & 3);       // 0..24
                #pragma unroll
                for (int jj = 0; jj < 8; ++jj) {
                    *(float4*)&Zs[(jl + jj) * 132 + 8 * et]     = make_float4(qa[0][jj], qa[1][jj], qa[2][jj], qa[3][jj]);
                    *(float4*)&Zs[(jl + jj) * 132 + 8 * et + 4] = make_float4(qa[4][jj], qa[5][jj], qa[6][jj], qa[7][jj]);
                }
            }
            {   // stage W2s rows: global j = jc + 32p + r
                int r = tid >> 3, q = tid & 7;
                *(float4*)&W2s[r * 36 + 4 * q] = *(const float4*)(W2p + (size_t)(jc + 32 * p + r) * 32 + 4 * q);
            }
            __syncthreads();
            #pragma unroll 4
            for (int kk = 0; kk < 32; ++kk) {
                float4 z4 = *(const float4*)&Zs[kk * 132 + 4 * eg];
                float4 w4 = *(const float4*)&W2s[kk * 36 + 4 * cq];
                accm[0] = f4fma(z4.x, w4, accm[0]);
                accm[1] = f4fma(z4.y, w4, accm[1]);
                accm[2] = f4fma(z4.z, w4, accm[2]);
                accm[3] = f4fma(z4.w, w4, accm[3]);
            }
        }
    }

    // ---- epilogue: m2 = silu(accm + b2), LN, scatter ----
    __syncthreads();
    float* m2s = Zs;   // [128][33]
    {
        float4 bb2 = *(const float4*)&cpar[4 * cq];
        #pragma unroll
        for (int i = 0; i < 4; ++i) {
            int e = 4 * eg + i;
            m2s[e * 33 + 4 * cq + 0] = silu(accm[i].x + bb2.x);
            m2s[e * 33 + 4 * cq + 1] = silu(accm[i].y + bb2.y);
            m2s[e * 33 + 4 * cq + 2] = silu(accm[i].z + bb2.z);
            m2s[e * 33 + 4 * cq + 3] = silu(accm[i].w + bb2.w);
        }
    }
    __syncthreads();
    if (tid < EPB) {
        float s = 0.f, ss = 0.f;
        float v[32];
        #pragma unroll
        for (int c = 0; c < 32; ++c) {
            float x = m2s[tid * 33 + c];
            v[c] = x; s += x; ss += x * x;
        }
        float mean = s * 0.03125f;
        float var = ss * 0.03125f - mean * mean;
        float rstd = 1.0f / sqrtf(var + EPS);
        int d = dsi[tid];
        float* Sp = S + (size_t)d * 32;
        #pragma unroll
        for (int c = 0; c < 32; ++c) {
            float y = (v[c] - mean) * rstd * cpar[32 + c] + cpar[64 + c];
            atomicAdd(&Sp[c], y);
        }
        atomicAdd(&cnt[d], 1.0f);
    }
}

// ---------------- node prep: H0 = [LN(feats) | LN(S/cnt)] ----------------
__global__ __launch_bounds__(128) void k_prep(const float* __restrict__ featsk,
                                              const float* __restrict__ S,
                                              const float* __restrict__ cnt,
                                              const float* __restrict__ nn1g,
                                              const float* __restrict__ nn1b,
                                              const float* __restrict__ eng,
                                              const float* __restrict__ enb,
                                              float* __restrict__ H0) {
    int n = blockIdx.x, tid = threadIdx.x;
    __shared__ float red[4];
    float x = featsk[(size_t)n * 768 + tid];
    float s = wave_sum64(x), ss = wave_sum64(x * x);
    if ((tid & 63) == 0) { red[(tid >> 6) * 2] = s; red[(tid >> 6) * 2 + 1] = ss; }
    __syncthreads();
    float S1 = red[0] + red[2], S2 = red[1] + red[3];
    float mean = S1 * (1.0f / 128.0f);
    float var = S2 * (1.0f / 128.0f) - mean * mean;
    float rstd = 1.0f / sqrtf(var + EPS);
    H0[(size_t)n * 160 + tid] = (x - mean) * rstd * nn1g[tid] + nn1b[tid];
    if (tid < 32) {
        float inv = 1.0f / fmaxf(cnt[n], 1.0f);
        float v = S[(size_t)n * 32 + tid] * inv;
        float s2 = v, q2 = v * v;
        #pragma unroll
        for (int off = 16; off > 0; off >>= 1) {
            s2 += __shfl_xor(s2, off, 64);
            q2 += __shfl_xor(q2, off, 64);
        }
        float m2 = s2 * (1.0f / 32.0f);
        float va = q2 * (1.0f / 32.0f) - m2 * m2;
        float rs = 1.0f / sqrtf(va + EPS);
        H0[(size_t)n * 160 + 128 + tid] = (v - m2) * rs * eng[tid] + enb[tid];
    }
}

// ---------------- LN + residual ----------------
__global__ __launch_bounds__(128) void k_ln_res(const float* __restrict__ H2,
                                                float* __restrict__ feats_all, int k,
                                                const float* __restrict__ g,
                                                const float* __restrict__ b) {
    int n = blockIdx.x, tid = threadIdx.x;
    __shared__ float red[4];
    float x = H2[(size_t)n * 128 + tid];
    float s = wave_sum64(x), ss = wave_sum64(x * x);
    if ((tid & 63) == 0) { red[(tid >> 6) * 2] = s; red[(tid >> 6) * 2 + 1] = ss; }
    __syncthreads();
    float S1 = red[0] + red[2], S2 = red[1] + red[3];
    float mean = S1 * (1.0f / 128.0f);
    float var = S2 * (1.0f / 128.0f) - mean * mean;
    float rstd = 1.0f / sqrtf(var + EPS);
    float v = (x - mean) * rstd * g[tid] + b[tid];
    float f = feats_all[(size_t)n * 768 + k * 128 + tid];
    feats_all[(size_t)n * 768 + (k + 1) * 128 + tid] = f + v;
}

// ---------------- graph pooling (batch sorted -> run-length accum) ----------------
__global__ __launch_bounds__(256) void k_pool(const float* __restrict__ F,
                                              const int* __restrict__ batch,
                                              float* __restrict__ G,
                                              float* __restrict__ cntg) {
    __shared__ int bL[32];
    int b0 = blockIdx.x * 32;
    int tid = threadIdx.x;
    int nmax = min(32, N_NODES - b0);
    if (nmax <= 0) return;
    if (tid < nmax) bL[tid] = batch[b0 + tid];
    __syncthreads();
    float accv = 0.f;
    int cur = -1;
    for (int i = 0; i < nmax; ++i) {
        int g = bL[i];
        if (g != cur) {
            if (cur >= 0) atomicAdd(&G[(size_t)cur * 256 + tid], accv);
            cur = g; accv = 0.f;
        }
        accv += F[(size_t)(b0 + i) * 256 + tid];
    }
    if (cur >= 0) atomicAdd(&G[(size_t)cur * 256 + tid], accv);
    if (tid == 0)
        for (int i = 0; i < nmax; ++i) atomicAdd(&cntg[bL[i]], 1.0f);
}

// ---------------- per-graph MLP head ----------------
__global__ __launch_bounds__(256) void k_graph(const float* __restrict__ G,
                                               const float* __restrict__ cntg,
                                               const float* __restrict__ g1W,
                                               const float* __restrict__ g1b,
                                               const float* __restrict__ g2W,
                                               const float* __restrict__ g2b,
                                               const float* __restrict__ g3W,
                                               const float* __restrict__ g3b,
                                               float* __restrict__ out) {
    __shared__ float X[256], Y[256], red[4];
    int g = blockIdx.x, tid = threadIdx.x;
    float inv = 1.0f / fmaxf(cntg[g], 1.0f);
    X[tid] = G[(size_t)g * 256 + tid] * inv;
    __syncthreads();
    float a = g1b[tid];
    for (int j = 0; j < 256; ++j) a = fmaf(X[j], g1W[(size_t)j * 256 + tid], a);
    Y[tid] = silu(a);
    __syncthreads();
    a = g2b[tid];
    for (int j = 0; j < 256; ++j) a = fmaf(Y[j], g2W[(size_t)j * 256 + tid], a);
    float z = silu(a);
    float p = z * g3W[tid];
    p = wave_sum64(p);
    if ((tid & 63) == 0) red[tid >> 6] = p;
    __syncthreads();
    if (tid == 0) out[g] = red[0] + red[1] + red[2] + red[3] + g3b[0];
}

extern "C" void kernel_launch(void* const* d_in, const int* in_sizes, int n_in,
                              void* d_out, int out_size, void* d_ws, size_t ws_size,
                              hipStream_t stream) {
    const int*   atomids = (const int*)d_in[0];
    const float* coords  = (const float*)d_in[1];
    const int*   eidx    = (const int*)d_in[2];
    const int*   batch   = (const int*)d_in[3];
    const float* emb_w   = (const float*)d_in[4];
    const float* eW1     = (const float*)d_in[5];
    const float* eb1     = (const float*)d_in[6];
    const float* eW2     = (const float*)d_in[7];
    const float* eb2     = (const float*)d_in[8];
    const float* en_g    = (const float*)d_in[9];
    const float* en_b    = (const float*)d_in[10];
    const float* nn1_g   = (const float*)d_in[11];
    const float* nn1_b   = (const float*)d_in[12];
    const float* nW1     = (const float*)d_in[13];
    const float* nb1     = (const float*)d_in[14];
    const float* nW2     = (const float*)d_in[15];
    const float* nb2     = (const float*)d_in[16];
    const float* nn2_g   = (const float*)d_in[17];
    const float* nn2_b   = (const float*)d_in[18];
    const float* f1W     = (const float*)d_in[19];
    const float* f1b     = (const float*)d_in[20];
    const float* f2W     = (const float*)d_in[21];
    const float* f2b     = (const float*)d_in[22];
    const float* f3W     = (const float*)d_in[23];
    const float* f3b     = (const float*)d_in[24];
    const float* g1W     = (const float*)d_in[25];
    const float* g1b     = (const float*)d_in[26];
    const float* g2W     = (const float*)d_in[27];
    const float* g2b     = (const float*)d_in[28];
    const float* g3W     = (const float*)d_in[29];
    const float* g3b     = (const float*)d_in[30];
    float* out = (float*)d_out;

    float* ws = (float*)d_ws;
    // layout (float indices, 16B-aligned); total ~34.06M floats ~= 136.3 MB
    float* feats_all = ws;                        // [10000][768]
    float* feT   = ws + 7680000;                  // [65][160000]
    float* Pab   = ws + 18080000;                 // [10000][1536]
    float* S     = ws + 33440000;                 // [10000][32]
    float* cnt   = ws + 33760000;                 // [10000]
    float* W1ab  = ws + 33770000;                 // [128][1536]
    float* W1cp  = ws + 33966608;                 // [65][768]
    float* b1p   = ws + 34016528;                 // [768]
    float* W2p   = ws + 34017296;                 // [768][32]
    float* G     = ws + 34041872;                 // [64][256]
    float* cntg  = ws + 34058256;                 // [64]
    // node-phase temporaries overlay Pab (dead between phases)
    float* H0 = Pab;                              // [10000][160]
    float* H1 = Pab + 1600000;                    // [10000][256]
    float* H2 = Pab + 4160000;                    // [10000][128]
    float* F1 = Pab;                              // [10000][256]
    float* F2 = Pab + 2560000;                    // [10000][256]
    float* F3 = Pab + 5120000;                    // [10000][256]

    k_embed<<<N_NODES, 128, 0, stream>>>(atomids, emb_w, feats_all);
    k_fe<<<N_EDGES / 64, 64, 0, stream>>>(coords, eidx, feT);

    for (int k = 0; k < NK; ++k) {
        const float* eW1k = eW1 + (size_t)k * 321 * 642;
        const float* eb1k = eb1 + (size_t)k * 642;
        const float* eW2k = eW2 + (size_t)k * 642 * 32;
        const float* eb2k = eb2 + (size_t)k * 32;
        const float* engk = en_g + (size_t)k * 32;
        const float* enbk = en_b + (size_t)k * 32;
        const float* nn1gk = nn1_g + (size_t)k * 128;
        const float* nn1bk = nn1_b + (size_t)k * 128;
        const float* nW1k = nW1 + (size_t)k * 160 * 256;
        const float* nb1k = nb1 + (size_t)k * 256;
        const float* nW2k = nW2 + (size_t)k * 256 * 128;
        const float* nb2k = nb2 + (size_t)k * 128;
        const float* nn2gk = nn2_g + (size_t)k * 128;
        const float* nn2bk = nn2_b + (size_t)k * 128;

        k_w1ab<<<768, 256, 0, stream>>>(eW1k, W1ab);
        k_wpre<<<294, 256, 0, stream>>>(eW1k, eb1k, eW2k, W1cp, b1p, W2p);
        k_gemm<<<dim3(79, 12), 256, 0, stream>>>(feats_all + k * 128, 768, W1ab, 1536,
                                                 nullptr, Pab, 1536, N_NODES, 1536, 128, 0, 0);
        hipMemsetAsync(S, 0, (size_t)330000 * sizeof(float), stream);
        k_edge<<<N_EDGES / EPB, 256, 0, stream>>>(feT, Pab, eidx, W1cp, b1p,
                                                  W2p, eb2k, engk, enbk, S, cnt);
        k_prep<<<N_NODES, 128, 0, stream>>>(feats_all + k * 128, S, cnt,
                                            nn1gk, nn1bk, engk, enbk, H0);
        k_gemm<<<dim3(79, 2), 256, 0, stream>>>(H0, 160, nW1k, 256, nb1k, H1, 256,
                                                N_NODES, 256, 160, 0, 1);
        k_gemm<<<dim3(79, 1), 256, 0, stream>>>(H1, 256, nW2k, 128, nb2k, H2, 128,
                                                N_NODES, 128, 256, 0, 0);
        k_ln_res<<<N_NODES, 128, 0, stream>>>(H2, feats_all, k, nn2gk, nn2bk);
    }

    // final node MLP (F1/F2/F3 overlay Pab)
    k_gemm<<<dim3(79, 2), 256, 0, stream>>>(feats_all, 768, f1W, 256, f1b, F1, 256,
                                            N_NODES, 256, 768, 1, 1);
    k_gemm<<<dim3(79, 2), 256, 0, stream>>>(F1, 256, f2W, 256, f2b, F2, 256,
                                            N_NODES, 256, 256, 0, 1);
    k_gemm<<<dim3(79, 2), 256, 0, stream>>>(F2, 256, f3W, 256, f3b, F3, 256,
                                            N_NODES, 256, 256, 0, 1);

    hipMemsetAsync(G, 0, (size_t)(16384 + 64) * sizeof(float), stream);
    k_pool<<<313, 256, 0, stream>>>(F3, batch, G, cntg);
    k_graph<<<N_GRAPHS, 256, 0, stream>>>(G, cntg, g1W, g1b, g2W, g2b, g3W, g3b, out);
}